// Round 1
// baseline (77.875 us; speedup 1.0000x reference)
//
#include <hip/hip_runtime.h>
#include <math.h>

// Output layout: [N][X=32][Y=32][Z=32][3] float32.
// val[n,x,y,z,d] = -0.5*t^2 - 0.5*log(2*pi),
//   t = ((idx_d - 15.5)*pitch - p[n,d]) / (conf[n]*pitch)
//     = idx_d*s - b_d   with s = pitch*inv, b_d = (15.5*pitch + p[n,d])*inv,
//       inv = 1/(conf[n]*pitch)   (ALPHA = 1)

#define HALF_LOG_2PI 0.91893853320467274178f

__global__ __launch_bounds__(256) void pbt_kernel(
    const float* __restrict__ points,
    const float* __restrict__ confs,
    const float* __restrict__ pitch_p,
    float* __restrict__ out)
{
    // One block per (n, x). Block writes 32*32*3 = 3072 contiguous floats.
    const unsigned block = blockIdx.x;
    const unsigned n = block >> 5;
    const unsigned x = block & 31u;

    const float pitch = pitch_p[0];
    const float conf  = confs[n];
    const float inv   = 1.0f / (conf * pitch);   // once per block, cheap
    const float s     = pitch * inv;
    const float off   = 15.5f * pitch;
    const float bx = (off + points[n * 3 + 0]) * inv;
    const float by = (off + points[n * 3 + 1]) * inv;
    const float bz = (off + points[n * 3 + 2]) * inv;

    const float tx = (float)x * s - bx;
    const float vx = fmaf(-0.5f * tx, tx, -HALF_LOG_2PI);

    float4* o = (float4*)(out + (size_t)block * 3072u);
    const unsigned t = threadIdx.x;

    #pragma unroll
    for (int k = 0; k < 3; ++k) {
        const unsigned f4 = t + (unsigned)k * 256u;  // float4 index, 0..767
        const unsigned e0 = f4 * 4u;                 // element index within block
        float v[4];
        #pragma unroll
        for (int j = 0; j < 4; ++j) {
            const unsigned e  = e0 + (unsigned)j;
            const unsigned d  = e % 3u;      // magic-mul
            const unsigned zi = e / 3u;      // 0..1023 -> (y,z)
            const unsigned y  = zi >> 5;
            const unsigned zz = zi & 31u;
            const float ty = (float)y  * s - by;
            const float tz = (float)zz * s - bz;
            const float vy = fmaf(-0.5f * ty, ty, -HALF_LOG_2PI);
            const float vz = fmaf(-0.5f * tz, tz, -HALF_LOG_2PI);
            v[j] = (d == 0u) ? vx : ((d == 1u) ? vy : vz);
        }
        o[f4] = make_float4(v[0], v[1], v[2], v[3]);
    }
}

extern "C" void kernel_launch(void* const* d_in, const int* in_sizes, int n_in,
                              void* d_out, int out_size, void* d_ws, size_t ws_size,
                              hipStream_t stream) {
    const float* points = (const float*)d_in[0];  // [N,3]
    const float* confs  = (const float*)d_in[1];  // [N]
    // d_in[2] = coordinates [32,32,32,3] — recomputed from pitch on device
    const float* pitch  = (const float*)d_in[3];  // [1]
    float* out = (float*)d_out;

    const int N = in_sizes[0] / 3;        // 1024
    const int blocks = N * 32;            // one block per (n, x)
    pbt_kernel<<<dim3(blocks), dim3(256), 0, stream>>>(points, confs, pitch, out);
}